// Round 1
// baseline (35468.152 us; speedup 1.0000x reference)
//
#include <hip/hip_runtime.h>
#include <cmath>

#define D3   192
#define SZP  (D3*D3)        // 36864, z stride
#define NVOX (D3*D3*D3)     // 7077888
#define NTOT (2*NVOX)       // 14155776
#define NBLK (NTOT/256)     // 55296  (exact: NVOX % 256 == 0, so blocks never straddle volumes)

typedef unsigned char u8;

struct Taps13 { float k[13]; };

__device__ __forceinline__ void coords(int idx, int& x, int& y, int& z, int& b) {
  x = idx % D3;
  y = (idx / D3) % D3;
  z = (idx / SZP) % D3;
  b = idx / NVOX;
}

// 1D 'same' zero-padded correlation along AXIS; accumulation order i=-R..R
// with separate rn mul/add to match XLA's un-contracted  out = out + k[i]*v.
template<int AXIS, int R>
__global__ void __launch_bounds__(256) conv1d_k(const float* __restrict__ in,
                                                float* __restrict__ out, Taps13 t) {
  int idx = blockIdx.x * 256 + threadIdx.x;
  int x, y, z, b; coords(idx, x, y, z, b);
  int c = (AXIS == 0) ? z : (AXIS == 1) ? y : x;
  const int stride = (AXIS == 0) ? SZP : (AXIS == 1) ? D3 : 1;
  float acc = 0.f;
#pragma unroll
  for (int i = -R; i <= R; ++i) {
    int cc = c + i;
    if (cc >= 0 && cc < D3)
      acc = __fadd_rn(acc, __fmul_rn(t.k[i + R], in[idx + i * stride]));
  }
  out[idx] = acc;
}

// fused fxx/fyy/fzz ([1,-2,1] stencils of s) + surfaceness + per-volume max
__global__ void __launch_bounds__(256) surf_k(const float* __restrict__ s,
                                              float* __restrict__ surf,
                                              unsigned int* __restrict__ mx,
                                              float scale) {
  int idx = blockIdx.x * 256 + threadIdx.x;
  int x, y, z, b; coords(idx, x, y, z, b);
  float ctr = s[idx];
  float fxx, fyy, fzz;
  { float acc = 0.f;
    if (z > 0)      acc = __fadd_rn(acc, __fmul_rn(1.f, s[idx - SZP]));
    acc = __fadd_rn(acc, __fmul_rn(-2.f, ctr));
    if (z < D3 - 1) acc = __fadd_rn(acc, __fmul_rn(1.f, s[idx + SZP]));
    fxx = __fmul_rn(acc, scale); }
  { float acc = 0.f;
    if (y > 0)      acc = __fadd_rn(acc, __fmul_rn(1.f, s[idx - D3]));
    acc = __fadd_rn(acc, __fmul_rn(-2.f, ctr));
    if (y < D3 - 1) acc = __fadd_rn(acc, __fmul_rn(1.f, s[idx + D3]));
    fyy = __fmul_rn(acc, scale); }
  { float acc = 0.f;
    if (x > 0)      acc = __fadd_rn(acc, __fmul_rn(1.f, s[idx - 1]));
    acc = __fadd_rn(acc, __fmul_rn(-2.f, ctr));
    if (x < D3 - 1) acc = __fadd_rn(acc, __fmul_rn(1.f, s[idx + 1]));
    fzz = __fmul_rn(acc, scale); }

  float num = __fadd_rn(__fmul_rn(fxx, fxx), __fmul_rn(fyy, fyy));
  float den = __fmul_rn(0.25f, __fadd_rn(__fmul_rn(fzz, fzz), 1e-7f));
  float arg = __fdiv_rn(-num, den);
  float sv  = __fmul_rn(expf(arg), fabsf(fzz));
  surf[idx] = sv;

  // block max -> one atomic per block (surf >= 0 so uint-bit ordering == float ordering)
  float m = sv;
  #pragma unroll
  for (int off = 32; off > 0; off >>= 1) m = fmaxf(m, __shfl_down(m, off));
  __shared__ float wred[4];
  int lane = threadIdx.x & 63, wid = threadIdx.x >> 6;
  if (lane == 0) wred[wid] = m;
  __syncthreads();
  if (threadIdx.x == 0) {
    float mm = fmaxf(fmaxf(wred[0], wred[1]), fmaxf(wred[2], wred[3]));
    atomicMax(&mx[b], __float_as_uint(mm));
  }
}

__global__ void __launch_bounds__(256) accum_k(float* __restrict__ C,
                                               const float* __restrict__ surf,
                                               const unsigned int* __restrict__ mx,
                                               int first) {
  int idx = blockIdx.x * 256 + threadIdx.x;
  int b = idx / NVOX;
  float m = __uint_as_float(mx[b]);
  float v = 0.f;
  if (m > 0.f) v = __fdiv_rn(surf[idx], __fadd_rn(m, 1e-7f));
  C[idx] = first ? v : fmaxf(C[idx], v);
}

__global__ void __launch_bounds__(256) mask_init_k(const float* __restrict__ v,
                                                   const float* __restrict__ C,
                                                   u8* __restrict__ low,
                                                   u8* __restrict__ m) {
  int idx = blockIdx.x * 256 + threadIdx.x;
  float vol = __fmul_rn(v[idx], C[idx]);
  low[idx] = vol > 0.5f ? 1 : 0;
  m[idx]   = vol > 0.9f ? 1 : 0;
}

__global__ void __launch_bounds__(256) hyst_k(const u8* __restrict__ mi,
                                              const u8* __restrict__ low,
                                              u8* __restrict__ mo) {
  int idx = blockIdx.x * 256 + threadIdx.x;
  int x, y, z, b; coords(idx, x, y, z, b);
  unsigned vv = mi[idx];
  if (x > 0)      vv |= mi[idx - 1];
  if (x < D3 - 1) vv |= mi[idx + 1];
  if (y > 0)      vv |= mi[idx - D3];
  if (y < D3 - 1) vv |= mi[idx + D3];
  if (z > 0)      vv |= mi[idx - SZP];
  if (z < D3 - 1) vv |= mi[idx + SZP];
  mo[idx] = (u8)(vv & low[idx]);
}

__global__ void __launch_bounds__(256) dilate_z_k(const u8* __restrict__ mi, u8* __restrict__ mo) {
  int idx = blockIdx.x * 256 + threadIdx.x;
  int z = (idx / SZP) % D3;
  unsigned vv = mi[idx];
  if (z > 0)      vv |= mi[idx - SZP];
  if (z < D3 - 1) vv |= mi[idx + SZP];
  mo[idx] = (u8)vv;
}

__global__ void __launch_bounds__(256) erode_z_k(const u8* __restrict__ mi, u8* __restrict__ mo) {
  int idx = blockIdx.x * 256 + threadIdx.x;
  int z = (idx / SZP) % D3;
  unsigned vv = mi[idx];
  if (z > 0)      vv &= mi[idx - SZP];
  if (z < D3 - 1) vv &= mi[idx + SZP];
  mo[idx] = (u8)vv;
}

__global__ void __launch_bounds__(256) label_init_k(const u8* __restrict__ closed,
                                                    int* __restrict__ lab) {
  int idx = blockIdx.x * 256 + threadIdx.x;
  lab[idx] = closed[idx] ? (idx % NVOX) + 1 : 0;
}

__global__ void __launch_bounds__(256) cc_k(const int* __restrict__ li,
                                            const u8* __restrict__ closed,
                                            int* __restrict__ lo) {
  int idx = blockIdx.x * 256 + threadIdx.x;
  int x, y, z, b; coords(idx, x, y, z, b);
  int vv = li[idx];
  if (x > 0)      vv = max(vv, li[idx - 1]);
  if (x < D3 - 1) vv = max(vv, li[idx + 1]);
  if (y > 0)      vv = max(vv, li[idx - D3]);
  if (y < D3 - 1) vv = max(vv, li[idx + D3]);
  if (z > 0)      vv = max(vv, li[idx - SZP]);
  if (z < D3 - 1) vv = max(vv, li[idx + SZP]);
  lo[idx] = closed[idx] ? vv : 0;
}

__global__ void __launch_bounds__(256) count_k(const int* __restrict__ lab,
                                               const u8* __restrict__ closed,
                                               unsigned int* __restrict__ counts) {
  int idx = blockIdx.x * 256 + threadIdx.x;
  if (closed[idx])
    atomicAdd(&counts[(idx / NVOX) * NVOX + (lab[idx] - 1)], 1u);
}

__global__ void __launch_bounds__(256) final_k(const int* __restrict__ lab,
                                               const u8* __restrict__ closed,
                                               const unsigned int* __restrict__ counts,
                                               float* __restrict__ out) {
  int idx = blockIdx.x * 256 + threadIdx.x;
  float r = 0.f;
  if (closed[idx]) {
    // read lab[idx] (may alias out[idx]) strictly before writing out[idx]
    int L = lab[idx];
    if (counts[(idx / NVOX) * NVOX + (L - 1)] >= 100u) r = 1.f;
  }
  out[idx] = r;
}

// ---- host-side: emulate numpy f32 pairwise sum exactly ----
static float np_sum_f32(const float* a, int n) {
  if (n < 8) { float res = 0.f; for (int i = 0; i < n; i++) res += a[i]; return res; }
  float r[8]; for (int j = 0; j < 8; j++) r[j] = a[j];
  int i = 8;
  for (; i < n - (n % 8); i += 8) for (int j = 0; j < 8; j++) r[j] += a[i + j];
  float res = ((r[0] + r[1]) + (r[2] + r[3])) + ((r[4] + r[5]) + (r[6] + r[7]));
  for (; i < n; i++) res += a[i];
  return res;
}

extern "C" void kernel_launch(void* const* d_in, const int* in_sizes, int n_in,
                              void* d_out, int out_size, void* d_ws, size_t ws_size,
                              hipStream_t stream) {
  const float* v = (const float*)d_in[0];
  float* out = (float*)d_out;
  char* base = (char*)d_ws;
  const size_t SZBUF = (size_t)NTOT * 4;

  // layout:  ws[0..SZBUF)   = A (f32 temp; later the 4 u8 masks fit in this footprint)
  //          ws[SZBUF..2S)  = Cf (surfaceness; later label pong; later counts)
  //          ws[2S..2S+8)   = mx[2]
  //          d_out          = Bf (f32 temp / surf / label ping) — fully rewritten before reads
  float* A  = (float*)base;
  float* Cf = (float*)(base + SZBUF);
  unsigned int* mx = (unsigned int*)(base + 2 * SZBUF);
  float* Bf = (float*)d_out;

  u8* low    = (u8*)base;
  u8* mA     = (u8*)(base + (size_t)NTOT);
  u8* mB     = (u8*)(base + (size_t)NTOT * 2);
  u8* closed = (u8*)(base + (size_t)NTOT * 3);
  int* labA  = (int*)Bf;
  int* labB  = (int*)Cf;
  unsigned int* counts = (unsigned int*)Cf;   // reused after CC (labels end in labA)

  dim3 g(NBLK), blk(256);

  const double sigmas[2] = {1.0, 2.0};
  for (int si = 0; si < 2; ++si) {
    double sigma = sigmas[si];
    int r = (int)(3.0 * sigma + 0.5);
    int n = 2 * r + 1;
    float a[13], k[13];
    for (int i = 0; i < n; i++) {
      float xx = (float)(i - r);
      float t  = xx * xx;
      float arg = -(t) / (float)(2.0 * sigma * sigma);   // exact in f32 for these sigmas
      a[i] = (float)std::exp((double)arg);                // correctly-rounded f32 exp
    }
    float ssum = np_sum_f32(a, n);
    for (int i = 0; i < n; i++) k[i] = a[i] / ssum;       // f32 division, as numpy

    Taps13 T = {};
    for (int i = 0; i < n; i++) T.k[i] = k[i];
    float scale = (float)(sigma * sigma);

    if (r == 3) {
      conv1d_k<0, 3><<<g, blk, 0, stream>>>(v,  A,  T);
      conv1d_k<1, 3><<<g, blk, 0, stream>>>(A,  Bf, T);
      conv1d_k<2, 3><<<g, blk, 0, stream>>>(Bf, A,  T);
    } else {
      conv1d_k<0, 6><<<g, blk, 0, stream>>>(v,  A,  T);
      conv1d_k<1, 6><<<g, blk, 0, stream>>>(A,  Bf, T);
      conv1d_k<2, 6><<<g, blk, 0, stream>>>(Bf, A,  T);
    }
    hipMemsetAsync(mx, 0, 8, stream);
    surf_k<<<g, blk, 0, stream>>>(A, Bf, mx, scale);
    accum_k<<<g, blk, 0, stream>>>(Cf, Bf, mx, si == 0 ? 1 : 0);
  }

  // thresholds + flood fill (exactly 256 one-step iterations == reference's capped loop)
  mask_init_k<<<g, blk, 0, stream>>>(v, Cf, low, mA);
  for (int it = 0; it < 256; ++it) {
    const u8* src = (it & 1) ? mB : mA;
    u8*       dst = (it & 1) ? mA : mB;
    hyst_k<<<g, blk, 0, stream>>>(src, low, dst);
  }
  // 256 iterations (even) -> result in mA

  dilate_z_k<<<g, blk, 0, stream>>>(mA, mB);
  erode_z_k<<<g, blk, 0, stream>>>(mB, closed);

  // CC max-label propagation (exactly 256 iterations == reference's capped loop)
  label_init_k<<<g, blk, 0, stream>>>(closed, labA);
  for (int it = 0; it < 256; ++it) {
    const int* src = (it & 1) ? labB : labA;
    int*       dst = (it & 1) ? labA : labB;
    cc_k<<<g, blk, 0, stream>>>(src, closed, dst);
  }
  // result in labA (== d_out region, reused as int labels)

  hipMemsetAsync(counts, 0, SZBUF, stream);
  count_k<<<g, blk, 0, stream>>>(labA, closed, counts);
  final_k<<<g, blk, 0, stream>>>(labA, closed, counts, out);
}

// Round 2
// 9024.336 us; speedup vs baseline: 3.9303x; 3.9303x over previous
//
#include <hip/hip_runtime.h>
#include <cmath>

#define D3   192
#define SZP  (D3*D3)        // 36864, z stride
#define NVOX (D3*D3*D3)     // 7077888
#define NTOT (2*NVOX)       // 14155776
#define NBLK (NTOT/256)     // 55296
#define W3   (NTOT/64)      // 221184 packed words total
#define WBLK (W3/256)       // 864

typedef unsigned char u8;
typedef unsigned long long u64;

struct Taps13 { float k[13]; };

__device__ __forceinline__ void coords(int idx, int& x, int& y, int& z, int& b) {
  x = idx % D3;
  y = (idx / D3) % D3;
  z = (idx / SZP) % D3;
  b = idx / NVOX;
}

// 1D 'same' zero-padded correlation along AXIS; accumulation order i=-R..R
// with separate rn mul/add to match XLA's un-contracted  out = out + k[i]*v.
template<int AXIS, int R>
__global__ void __launch_bounds__(256) conv1d_k(const float* __restrict__ in,
                                                float* __restrict__ out, Taps13 t) {
  int idx = blockIdx.x * 256 + threadIdx.x;
  int x, y, z, b; coords(idx, x, y, z, b);
  int c = (AXIS == 0) ? z : (AXIS == 1) ? y : x;
  const int stride = (AXIS == 0) ? SZP : (AXIS == 1) ? D3 : 1;
  float acc = 0.f;
#pragma unroll
  for (int i = -R; i <= R; ++i) {
    int cc = c + i;
    if (cc >= 0 && cc < D3)
      acc = __fadd_rn(acc, __fmul_rn(t.k[i + R], in[idx + i * stride]));
  }
  out[idx] = acc;
}

// fused fxx/fyy/fzz ([1,-2,1] stencils of s) + surfaceness + per-volume max
__global__ void __launch_bounds__(256) surf_k(const float* __restrict__ s,
                                              float* __restrict__ surf,
                                              unsigned int* __restrict__ mx,
                                              float scale) {
  int idx = blockIdx.x * 256 + threadIdx.x;
  int x, y, z, b; coords(idx, x, y, z, b);
  float ctr = s[idx];
  float fxx, fyy, fzz;
  { float acc = 0.f;
    if (z > 0)      acc = __fadd_rn(acc, __fmul_rn(1.f, s[idx - SZP]));
    acc = __fadd_rn(acc, __fmul_rn(-2.f, ctr));
    if (z < D3 - 1) acc = __fadd_rn(acc, __fmul_rn(1.f, s[idx + SZP]));
    fxx = __fmul_rn(acc, scale); }
  { float acc = 0.f;
    if (y > 0)      acc = __fadd_rn(acc, __fmul_rn(1.f, s[idx - D3]));
    acc = __fadd_rn(acc, __fmul_rn(-2.f, ctr));
    if (y < D3 - 1) acc = __fadd_rn(acc, __fmul_rn(1.f, s[idx + D3]));
    fyy = __fmul_rn(acc, scale); }
  { float acc = 0.f;
    if (x > 0)      acc = __fadd_rn(acc, __fmul_rn(1.f, s[idx - 1]));
    acc = __fadd_rn(acc, __fmul_rn(-2.f, ctr));
    if (x < D3 - 1) acc = __fadd_rn(acc, __fmul_rn(1.f, s[idx + 1]));
    fzz = __fmul_rn(acc, scale); }

  float num = __fadd_rn(__fmul_rn(fxx, fxx), __fmul_rn(fyy, fyy));
  float den = __fmul_rn(0.25f, __fadd_rn(__fmul_rn(fzz, fzz), 1e-7f));
  float arg = __fdiv_rn(-num, den);
  float sv  = __fmul_rn(expf(arg), fabsf(fzz));
  surf[idx] = sv;

  float m = sv;
  #pragma unroll
  for (int off = 32; off > 0; off >>= 1) m = fmaxf(m, __shfl_down(m, off));
  __shared__ float wred[4];
  int lane = threadIdx.x & 63, wid = threadIdx.x >> 6;
  if (lane == 0) wred[wid] = m;
  __syncthreads();
  if (threadIdx.x == 0) {
    float mm = fmaxf(fmaxf(wred[0], wred[1]), fmaxf(wred[2], wred[3]));
    atomicMax(&mx[b], __float_as_uint(mm));
  }
}

__global__ void __launch_bounds__(256) accum_k(float* __restrict__ C,
                                               const float* __restrict__ surf,
                                               const unsigned int* __restrict__ mx,
                                               int first) {
  int idx = blockIdx.x * 256 + threadIdx.x;
  int b = idx / NVOX;
  float m = __uint_as_float(mx[b]);
  float v = 0.f;
  if (m > 0.f) v = __fdiv_rn(surf[idx], __fadd_rn(m, 1e-7f));
  C[idx] = first ? v : fmaxf(C[idx], v);
}

// thresholds -> bit-packed masks via wave ballot (wave=64 <-> one u64 word)
__global__ void __launch_bounds__(256) mask_init_pack_k(const float* __restrict__ v,
                                                        const float* __restrict__ C,
                                                        u64* __restrict__ lowW,
                                                        u64* __restrict__ mW) {
  int idx = blockIdx.x * 256 + threadIdx.x;
  float vol = __fmul_rn(v[idx], C[idx]);
  u64 bl = __ballot(vol > 0.5f);
  u64 bh = __ballot(vol > 0.9f);
  if ((threadIdx.x & 63) == 0) {
    lowW[idx >> 6] = bl;
    mW[idx >> 6]   = bh;
  }
}

// one synchronous flood-fill step on packed words
// word w = xw + 3*y + 576*z + 110592*b  (bit i = voxel x = 64*xw + i)
__global__ void __launch_bounds__(256) hyst_pack_k(const u64* __restrict__ mi,
                                                   const u64* __restrict__ lowW,
                                                   u64* __restrict__ mo) {
  int w = blockIdx.x * 256 + threadIdx.x;   // W3 == gridDim*256 exactly
  int xw = w % 3;
  int y  = (w / 3) % D3;
  int z  = (w / 576) % D3;
  u64 m = mi[w];
  u64 v = m | (m << 1) | (m >> 1);
  if (xw > 0)      v |= mi[w - 1] >> 63;
  if (xw < 2)      v |= mi[w + 1] << 63;
  if (y > 0)       v |= mi[w - 3];
  if (y < D3 - 1)  v |= mi[w + 3];
  if (z > 0)       v |= mi[w - 576];
  if (z < D3 - 1)  v |= mi[w + 576];
  mo[w] = v & lowW[w];
}

// fused z-closing (dilate r=1 then erode r=1, box SE), packed words
__global__ void __launch_bounds__(256) close_z_k(const u64* __restrict__ mi,
                                                 u64* __restrict__ mo) {
  int w = blockIdx.x * 256 + threadIdx.x;
  int z = (w / 576) % D3;
  u64 c   = mi[w];
  u64 zm1 = (z > 0)      ? mi[w - 576]  : 0ull;
  u64 zm2 = (z > 1)      ? mi[w - 1152] : 0ull;
  u64 zp1 = (z < D3 - 1) ? mi[w + 576]  : 0ull;
  u64 zp2 = (z < D3 - 2) ? mi[w + 1152] : 0ull;
  u64 d0 = c | zm1 | zp1;        // dilated at z
  u64 e  = d0;
  if (z > 0)      e &= (zm2 | zm1 | c);   // dilated at z-1
  if (z < D3 - 1) e &= (c | zp1 | zp2);   // dilated at z+1
  mo[w] = e;
}

__global__ void __launch_bounds__(256) label_init_k(const u64* __restrict__ closedW,
                                                    int* __restrict__ lab) {
  int idx = blockIdx.x * 256 + threadIdx.x;
  int bit = (int)((closedW[idx >> 6] >> (idx & 63)) & 1ull);
  lab[idx] = bit ? (idx % NVOX) + 1 : 0;
}

// one synchronous max-propagation step; closed <=> lab>0 (labels start >=1, never decrease)
__global__ void __launch_bounds__(256) cc_k(const int* __restrict__ li,
                                            int* __restrict__ lo) {
  int idx = blockIdx.x * 256 + threadIdx.x;
  int s = li[idx];
  if (s == 0) { lo[idx] = 0; return; }
  int x, y, z, b; coords(idx, x, y, z, b);
  if (x > 0)      s = max(s, li[idx - 1]);
  if (x < D3 - 1) s = max(s, li[idx + 1]);
  if (y > 0)      s = max(s, li[idx - D3]);
  if (y < D3 - 1) s = max(s, li[idx + D3]);
  if (z > 0)      s = max(s, li[idx - SZP]);
  if (z < D3 - 1) s = max(s, li[idx + SZP]);
  lo[idx] = s;
}

__global__ void __launch_bounds__(256) count_k(const int* __restrict__ lab,
                                               unsigned int* __restrict__ counts) {
  int idx = blockIdx.x * 256 + threadIdx.x;
  int L = lab[idx];
  if (L > 0)
    atomicAdd(&counts[(idx / NVOX) * NVOX + (L - 1)], 1u);
}

__global__ void __launch_bounds__(256) final_k(const int* __restrict__ lab,
                                               const unsigned int* __restrict__ counts,
                                               float* __restrict__ out) {
  int idx = blockIdx.x * 256 + threadIdx.x;
  int L = lab[idx];   // lab may alias out: read strictly before write
  float r = (L > 0 && counts[(idx / NVOX) * NVOX + (L - 1)] >= 100u) ? 1.f : 0.f;
  out[idx] = r;
}

// ---- host-side: emulate numpy f32 pairwise sum exactly ----
static float np_sum_f32(const float* a, int n) {
  if (n < 8) { float res = 0.f; for (int i = 0; i < n; i++) res += a[i]; return res; }
  float r[8]; for (int j = 0; j < 8; j++) r[j] = a[j];
  int i = 8;
  for (; i < n - (n % 8); i += 8) for (int j = 0; j < 8; j++) r[j] += a[i + j];
  float res = ((r[0] + r[1]) + (r[2] + r[3])) + ((r[4] + r[5]) + (r[6] + r[7]));
  for (; i < n; i++) res += a[i];
  return res;
}

extern "C" void kernel_launch(void* const* d_in, const int* in_sizes, int n_in,
                              void* d_out, int out_size, void* d_ws, size_t ws_size,
                              hipStream_t stream) {
  const float* v = (const float*)d_in[0];
  float* out = (float*)d_out;
  char* base = (char*)d_ws;
  const size_t SZBUF = (size_t)NTOT * 4;

  // ws layout:
  //   [0 .. S)      A  : conv temp (f32).  After surfs done: packed masks live here.
  //   [S .. 2S)     Cf : surfaceness accum (f32). After mask_init: labB; then counts.
  //   [2S .. 2S+8)  mx[2]
  //   d_out         Bf : conv temp / surf (f32); then labA (final labels); then out.
  float* A  = (float*)base;
  float* Cf = (float*)(base + SZBUF);
  unsigned int* mx = (unsigned int*)(base + 2 * SZBUF);
  float* Bf = (float*)d_out;

  const size_t SZW = (size_t)W3 * 8;      // 1.77 MB per packed mask
  u64* lowW    = (u64*)base;
  u64* mWA     = (u64*)(base + SZW);
  u64* mWB     = (u64*)(base + 2 * SZW);
  u64* closedW = (u64*)(base + 3 * SZW);

  int* labA = (int*)Bf;
  int* labB = (int*)Cf;
  unsigned int* counts = (unsigned int*)Cf;

  dim3 g(NBLK), gw(WBLK), blk(256);

  const double sigmas[2] = {1.0, 2.0};
  for (int si = 0; si < 2; ++si) {
    double sigma = sigmas[si];
    int r = (int)(3.0 * sigma + 0.5);
    int n = 2 * r + 1;
    float a[13], k[13];
    for (int i = 0; i < n; i++) {
      float xx = (float)(i - r);
      float t  = xx * xx;
      float arg = -(t) / (float)(2.0 * sigma * sigma);
      a[i] = (float)std::exp((double)arg);
    }
    float ssum = np_sum_f32(a, n);
    for (int i = 0; i < n; i++) k[i] = a[i] / ssum;

    Taps13 T = {};
    for (int i = 0; i < n; i++) T.k[i] = k[i];
    float scale = (float)(sigma * sigma);

    if (r == 3) {
      conv1d_k<0, 3><<<g, blk, 0, stream>>>(v,  A,  T);
      conv1d_k<1, 3><<<g, blk, 0, stream>>>(A,  Bf, T);
      conv1d_k<2, 3><<<g, blk, 0, stream>>>(Bf, A,  T);
    } else {
      conv1d_k<0, 6><<<g, blk, 0, stream>>>(v,  A,  T);
      conv1d_k<1, 6><<<g, blk, 0, stream>>>(A,  Bf, T);
      conv1d_k<2, 6><<<g, blk, 0, stream>>>(Bf, A,  T);
    }
    hipMemsetAsync(mx, 0, 8, stream);
    surf_k<<<g, blk, 0, stream>>>(A, Bf, mx, scale);
    accum_k<<<g, blk, 0, stream>>>(Cf, Bf, mx, si == 0 ? 1 : 0);
  }

  // thresholds -> packed masks (A's f32 data dead from here; packed masks reuse it)
  mask_init_pack_k<<<g, blk, 0, stream>>>(v, Cf, lowW, mWA);

  // flood fill: exactly 256 one-step iterations == reference's capped while_loop
  for (int it = 0; it < 256; ++it) {
    const u64* src = (it & 1) ? mWB : mWA;
    u64*       dst = (it & 1) ? mWA : mWB;
    hyst_pack_k<<<gw, blk, 0, stream>>>(src, lowW, dst);
  }
  // 256 (even) iterations -> result in mWA

  close_z_k<<<gw, blk, 0, stream>>>(mWA, closedW);

  // CC max-label propagation: exactly 256 iterations (Cf dead -> labB)
  label_init_k<<<g, blk, 0, stream>>>(closedW, labA);
  for (int it = 0; it < 256; ++it) {
    const int* src = (it & 1) ? labB : labA;
    int*       dst = (it & 1) ? labA : labB;
    cc_k<<<g, blk, 0, stream>>>(src, dst);
  }
  // result in labA (== d_out region)

  hipMemsetAsync(counts, 0, SZBUF, stream);
  count_k<<<g, blk, 0, stream>>>(labA, counts);
  final_k<<<g, blk, 0, stream>>>(labA, counts, out);
}